// Round 6
// baseline (654.056 us; speedup 1.0000x reference)
//
#include <hip/hip_runtime.h>
#include <hip/hip_bf16.h>
#include <type_traits>
#include <math.h>

// ---------------------------------------------------------------------------
// Attention: out = softmax_causal((x Wq^T + bq)(x Wk^T + bk)^T / sqrt(D)) (x Wv^T + bv) Wp^T + bp
// B=4, S=2048, D=2048, fp32 in/out, bf16 MFMA compute.
//
// R9: dispatch-balance round. R4-R8 established the 256^2 loop is stuck at
// ~5300 cyc/K-tile (additive LDS+MFMA) under every fence/schedule variant;
// meanwhile scores (144 blocks, all K=2048 deep: wall = 70us for 39 GFLOP)
// and PV (256 blocks, causal depth 4..32 K-tiles: wall = deepest) are
// dispatch-bound. Changes:
//   1. scores + PV moved to the PROVEN 128^2 kernel (verbatim R0 baseline):
//      544 / 1024 blocks, 2-4 per CU, ~5 co-resident (32KiB LDS) -> work-bound.
//   2. softmax writes only [0, (q&~255)+256) -- the PV-128 read limit is
//      ceil128(q+1) <= ceil256(q+1); region beyond is never read. Halves W.
//   3. 256^2 loop (qkv + proj only): a01-next reads moved from the ph4 burst
//      (12->8 reads) to own-phase ph1. Ledger: LGK(4)@ph1 covers {8 bfr
//      refills(ph4) + 4 a01} done, own 4 a23 in flight; ph2/ph3 unchanged;
//      vmcnt schedule identical to R8; STG A0 still after the LGK(0)+BAR gate.
//
// 256^2 schedule per K-tile (4 phases):
//   ph1{rd a01,a23 | STG A1(kt+1)->nb | BAR | LGK(4) | MFMA m01 | BAR}
//   ph2{rd a45 | STG B0(kt+2)->bc | BAR | LGK(4) | MFMA m23 | BAR}
//   ph3{rd a67 | STG B1(kt+2)->bc | BAR | LGK(4) | MFMA m45 | BAR}
//   ph4{vmcnt(4); lgkmcnt(0); BAR | 4x{MFMA m67 slice n; refill bfr[n] from
//       nb} | STG A0(kt+2)->bc | BAR}
// vmcnt ledger: carried-in 6 {B0,B1,A0}(kt+1); +A1@ph1 +B0@ph2 +B1@ph3 = 12;
// vmcnt(4) lands oldest 8 = tile kt+1 complete; +A0@ph4 -> carried 6. Wrapped
// k mod Keff past-the-end prefetch lands only in consumed regions.
// XOR slot swizzle kept (0 bank conflicts). Bijective XCD swizzle kept.
//
// Workspace layout (256 MB):
//   [0,32)MB    xb    bf16 x              [8192,2048]
//   [32,56)MB   wqkv  bf16 [Wq;Wk;Wv]     [6144,2048]
//   [56,64)MB   wpb   bf16 Wp             [2048,2048]
//   [64,96)MB   qb    bf16 Q              (later reused as attn P)
//   [96,128)MB  kb    bf16 K              (later reused as ctx)
//   [160,192)MB vtb   bf16 V^T per batch  [B][D][S]
//   [192,256)MB sc    fp32 scores         [B,S,S]
// ---------------------------------------------------------------------------

typedef __bf16 bf16x8_t __attribute__((ext_vector_type(8)));
typedef float f32x4_t __attribute__((ext_vector_type(4)));
typedef unsigned short u16x8_t __attribute__((ext_vector_type(8)));

__device__ inline unsigned short f2bf(float f) {
  unsigned int u = __builtin_bit_cast(unsigned int, f);
  unsigned int r = u + 0x7fffu + ((u >> 16) & 1u);
  return (unsigned short)(r >> 16);
}

// async global->LDS, 16B per lane; lds dest = wave-uniform base + lane*16
__device__ inline void gl2lds16(const unsigned short* g, unsigned short* l) {
  __builtin_amdgcn_global_load_lds(
      (const __attribute__((address_space(1))) unsigned int*)g,
      (__attribute__((address_space(3))) unsigned int*)l, 16, 0, 0);
}

// LDS byte-address of a generic pointer known to be in LDS
__device__ __forceinline__ unsigned as3base(const unsigned short* p) {
  return (unsigned)(unsigned long long)
      (const __attribute__((address_space(3))) unsigned short*)p;
}

// raw ds_read_b128, invisible to the waitcnt legalizer (manual lgkmcnt!)
__device__ __forceinline__ bf16x8_t ldsa(unsigned a) {
  bf16x8_t r;
  asm volatile("ds_read_b128 %0, %1" : "=v"(r) : "v"(a));
  return r;
}

#define MF(a_, b_, c_) \
  (c_) = __builtin_amdgcn_mfma_f32_16x16x32_bf16((a_), (b_), (c_), 0, 0, 0)
#define SB0() __builtin_amdgcn_sched_barrier(0)
#define BAR()                         \
  do {                                \
    SB0();                            \
    __builtin_amdgcn_s_barrier();     \
    SB0();                            \
  } while (0)
#define LGK(n_)                                          \
  do {                                                   \
    asm volatile("s_waitcnt lgkmcnt(" #n_ ")");          \
    SB0();                                               \
  } while (0)
#define VM4()                                   \
  do {                                          \
    asm volatile("s_waitcnt vmcnt(4)");         \
    SB0();                                      \
  } while (0)
#define VM6()                                   \
  do {                                          \
    asm volatile("s_waitcnt vmcnt(6)");         \
    SB0();                                      \
  } while (0)
#define PRIO(x) __builtin_amdgcn_s_setprio(x)

// ---------------- cast fp32 -> bf16 (x input) ------------------------------
__global__ __launch_bounds__(256) void cast_f32_bf16(
    const float* __restrict__ in, unsigned short* __restrict__ out, long n4) {
  long i = blockIdx.x * 256L + threadIdx.x;
  if (i >= n4) return;
  float4 f = ((const float4*)in)[i];
  ushort4 u;
  u.x = f2bf(f.x); u.y = f2bf(f.y); u.z = f2bf(f.z); u.w = f2bf(f.w);
  ((ushort4*)out)[i] = u;
}

// ---------------- fused 4-weight cast: blockIdx.y selects matrix -----------
__global__ __launch_bounds__(256) void cast_w4(
    const float* __restrict__ w0, const float* __restrict__ w1,
    const float* __restrict__ w2, const float* __restrict__ w3,
    unsigned short* __restrict__ o0, unsigned short* __restrict__ o1,
    unsigned short* __restrict__ o2, unsigned short* __restrict__ o3,
    long n4) {
  long i = blockIdx.x * 256L + threadIdx.x;
  if (i >= n4) return;
  const float* in; unsigned short* out;
  switch (blockIdx.y) {
    case 0: in = w0; out = o0; break;
    case 1: in = w1; out = o1; break;
    case 2: in = w2; out = o2; break;
    default: in = w3; out = o3; break;
  }
  float4 f = ((const float4*)in)[i];
  ushort4 u;
  u.x = f2bf(f.x); u.y = f2bf(f.y); u.z = f2bf(f.z); u.w = f2bf(f.w);
  ((ushort4*)out)[i] = u;
}

// ======================= 128^2 GEMM (verbatim R0 baseline) =================
// Used for the causal-shaped GEMMs (scores, PV) where dispatch balance wins:
// 32 KiB LDS -> ~5 blocks/CU co-resident; BK=64; XOR slot swizzle.
#define BM 128
#define BN 128
#define BK 64

#define GEMM_PROLOGUE()                                                        \
  const int tid = threadIdx.x;                                                 \
  const int lane = tid & 63;                                                   \
  const int wave = tid >> 6;                                                   \
  const int wm = (wave >> 1) * 64;                                             \
  const int wn = (wave & 1) * 64;                                              \
  __shared__ unsigned short smem[2 * BM * BK]; /* 32 KB */                     \
  unsigned short* As = smem;                                                   \
  unsigned short* Bs = smem + BM * BK;                                         \
  const int lr = lane >> 3;                                                    \
  const int swcol = ((lane & 7) ^ lr) * 8;                                     \
  const int cbase = wave * 4;                                                  \
  f32x4_t acc[4][4] = {};                                                      \
  const int fr = lane & 15;                                                    \
  const int q4 = lane >> 4;                                                    \
  const int fo0 = ((q4 ^ (fr & 7)) * 8);       /* kk=0 slot (swizzled) */      \
  const int fo1 = (((q4 + 4) ^ (fr & 7)) * 8); /* kk=1 slot (swizzled) */

#define GEMM_KLOOP(Ab, Bb, K, Keff)                                            \
  for (int k0 = 0; k0 < (Keff); k0 += BK) {                                    \
    __syncthreads();                                                           \
    _Pragma("unroll")                                                          \
    for (int i = 0; i < 4; i++) {                                              \
      const int c = cbase + i;                                                 \
      gl2lds16((Ab) + (size_t)(c * 8 + lr) * (K) + k0 + swcol, As + c * 512);  \
      gl2lds16((Bb) + (size_t)(c * 8 + lr) * (K) + k0 + swcol, Bs + c * 512);  \
    }                                                                          \
    __syncthreads();                                                           \
    {                                                                          \
      bf16x8_t af[4], bfv[4];                                                  \
      _Pragma("unroll")                                                        \
      for (int mi = 0; mi < 4; mi++)                                           \
        af[mi] = __builtin_bit_cast(                                           \
            bf16x8_t, *(const u16x8_t*)&As[(wm + mi * 16 + fr) * BK + fo0]);   \
      _Pragma("unroll")                                                        \
      for (int ni = 0; ni < 4; ni++)                                           \
        bfv[ni] = __builtin_bit_cast(                                          \
            bf16x8_t, *(const u16x8_t*)&Bs[(wn + ni * 16 + fr) * BK + fo0]);   \
      _Pragma("unroll")                                                        \
      for (int mi = 0; mi < 4; mi++)                                           \
        _Pragma("unroll")                                                      \
        for (int ni = 0; ni < 4; ni++)                                         \
          acc[mi][ni] = __builtin_amdgcn_mfma_f32_16x16x32_bf16(               \
              af[mi], bfv[ni], acc[mi][ni], 0, 0, 0);                          \
      _Pragma("unroll")                                                        \
      for (int mi = 0; mi < 4; mi++)                                           \
        af[mi] = __builtin_bit_cast(                                           \
            bf16x8_t, *(const u16x8_t*)&As[(wm + mi * 16 + fr) * BK + fo1]);   \
      _Pragma("unroll")                                                        \
      for (int ni = 0; ni < 4; ni++)                                           \
        bfv[ni] = __builtin_bit_cast(                                          \
            bf16x8_t, *(const u16x8_t*)&Bs[(wn + ni * 16 + fr) * BK + fo1]);   \
      _Pragma("unroll")                                                        \
      for (int mi = 0; mi < 4; mi++)                                           \
        _Pragma("unroll")                                                      \
        for (int ni = 0; ni < 4; ni++)                                         \
          acc[mi][ni] = __builtin_amdgcn_mfma_f32_16x16x32_bf16(               \
              af[mi], bfv[ni], acc[mi][ni], 0, 0, 0);                          \
    }                                                                          \
  }

// MODE 1: causal block skip. MODE 2: causal K-limit.
template <int MODE, typename OutT>
__global__ __launch_bounds__(256) void gemm128_nt(
    const unsigned short* __restrict__ A, const unsigned short* __restrict__ B,
    OutT* __restrict__ C, const float* __restrict__ bias, float alpha,
    int M, int N, int K, size_t sA, size_t sB, size_t sC) {
  const int bm = blockIdx.y * BM;
  const int bn = blockIdx.x * BN;
  if (MODE == 1 && bn >= bm + BM) return;
  int Keff = K;
  if (MODE == 2) { int kl = bm + BM; Keff = kl < K ? kl : K; }

  A += (size_t)blockIdx.z * sA;
  B += (size_t)blockIdx.z * sB;
  C += (size_t)blockIdx.z * sC;

  GEMM_PROLOGUE();
  const unsigned short* Ab = A + (size_t)bm * K;
  const unsigned short* Bb = B + (size_t)bn * K;
  GEMM_KLOOP(Ab, Bb, K, Keff);

  const int cr = (lane >> 4) * 4;
  const int cc = lane & 15;
#pragma unroll
  for (int ni = 0; ni < 4; ni++) {
    const int col = bn + wn + ni * 16 + cc;
    const float bs = bias ? bias[col] : 0.f;
#pragma unroll
    for (int mi = 0; mi < 4; mi++) {
      const int row = bm + wm + mi * 16 + cr;
#pragma unroll
      for (int r = 0; r < 4; r++) {
        float v = acc[mi][ni][r] * alpha + bs;
        if constexpr (std::is_same_v<OutT, float>)
          C[(size_t)(row + r) * N + col] = v;
        else
          C[(size_t)(row + r) * N + col] = f2bf(v);
      }
    }
  }
}

// ===================== 256^2 pipelined 4-phase K-loop ======================
// LDS bytes: buf b at b*65536; A0@0 A1@16384 B0@32768 B1@49152.
// Each half = [128 rows][64 cols] bf16, 16 KB; staged by 512 thr x 2 loads.
__device__ __forceinline__ void g256_kloop(
    const unsigned short* __restrict__ A, const unsigned short* __restrict__ B,
    int K, int Keff, unsigned short* smem, f32x4_t (&acc)[8][4]) {
  const int tid = threadIdx.x;
  const int lane = tid & 63;
  const int wave = tid >> 6;
  const int wr = wave >> 2;           // 0..1  (M half)
  const int wc = wave & 3;            // 0..3  (N quarter)
  const int fr = lane & 15;
  const int q4 = lane >> 4;
  // swizzled 16B slot byte-offsets (phys slot p of row r holds logical p^(r&7))
  const unsigned s0b = (unsigned)((q4 ^ (fr & 7)) * 16);        // kk=0
  const unsigned s1b = (unsigned)(((q4 + 4) ^ (fr & 7)) * 16);  // kk=1
  // staging: this thread's global offset (row + swizzled column)
  const size_t rowK =
      (size_t)(wave * 8 + (lane >> 3)) * (size_t)K +
      (size_t)(((lane & 7) ^ ((lane >> 3) & 7)) * 8);
  const size_t K64 = (size_t)64 * K;
  const size_t K128 = (size_t)128 * K;
  const int wofs = wave * 512;  // wave-uniform LDS chunk (1 KB, elems)
  const int NT = Keff >> 6;     // always >= 4 here
  const unsigned sb = as3base(smem);
  const unsigned aoffB = (unsigned)(wr * 16384 + fr * 128);
  const unsigned boffB =
      (unsigned)(32768 + (wc >> 1) * 16384 + (wc & 1) * 8192 + fr * 128);

#define STG(gp_, lh_)                        \
  do {                                       \
    const unsigned short* g_ = (gp_) + rowK; \
    gl2lds16(g_, (lh_) + wofs);              \
    gl2lds16(g_ + K64, (lh_) + 4096 + wofs); \
  } while (0)

#define MFMA8(mb_, af_)                          \
  _Pragma("unroll")                              \
  for (int n = 0; n < 4; ++n) {                  \
    MF(af_[0][0], bfr[n][0], acc[(mb_)][n]);     \
    MF(af_[0][1], bfr[n][1], acc[(mb_)][n]);     \
    MF(af_[1][0], bfr[n][0], acc[(mb_) + 1][n]); \
    MF(af_[1][1], bfr[n][1], acc[(mb_) + 1][n]); \
  }

#define RDA(dst_, baseB_, mo_)                                \
  _Pragma("unroll")                                           \
  for (int m = 0; m < 2; ++m) {                               \
    dst_[m][0] = ldsa((baseB_) + (m + (mo_)) * 2048u + s0b);  \
    dst_[m][1] = ldsa((baseB_) + (m + (mo_)) * 2048u + s1b);  \
  }

  // ---- prologue: tile0 {A0,A1,B0,B1} -> buf0; tile1 {B0,B1,A0} -> buf1 ----
  STG(A, smem);
  STG(A + K128, smem + 8192);
  STG(B, smem + 16384);
  STG(B + K128, smem + 24576);
  STG(B + 64, smem + 32768 + 16384);
  STG(B + K128 + 64, smem + 32768 + 24576);
  STG(A + 64, smem + 32768);
  VM6();   // tile0's 8 loads landed (per-wave); 6 in flight for tile1
  BAR();   // now landed for ALL waves

  bf16x8_t bfr[4][2], a01[2][2], a23[2][2], a45[2][2], a67[2][2];
  {  // tile0 B fragments (8 asm reads, left outstanding like steady state)
    const unsigned Bh = sb + boffB;
#pragma unroll
    for (int n = 0; n < 4; ++n) {
      bfr[n][0] = ldsa(Bh + n * 2048u + s0b);
      bfr[n][1] = ldsa(Bh + n * 2048u + s1b);
    }
  }

  for (int kt = 0; kt < NT; ++kt) {
    unsigned short* bcp = smem + ((kt & 1) << 15);       // compute buf (elems)
    unsigned short* nbp = smem + (((kt + 1) & 1) << 15); // next buf (elems)
    const unsigned AhcB = sb + ((unsigned)(kt & 1) << 16) + aoffB;
    const unsigned BhnB = sb + ((unsigned)((kt + 1) & 1) << 16) + boffB;
    int k1 = (kt + 1) << 6; if (k1 >= Keff) k1 -= Keff;  // wrap = safe garbage
    int k2 = (kt + 2) << 6; if (k2 >= Keff) k2 -= Keff;

    // ---- phase 1: rd a01(own)+a23; STG A1(kt+1)->nb; MFMA m0,1 -----------
    RDA(a01, AhcB, 0);
    RDA(a23, AhcB, 2);
    SB0();
    STG(A + K128 + k1, nbp + 8192);
    BAR();
    LGK(4);  // {8 bfr refills (prev ph4) + 4 a01} landed; own a23 in flight
    PRIO(1);
    MFMA8(0, a01);
    PRIO(0);
    BAR();

    // ---- phase 2: rd a45; STG B0(kt+2)->bc; MFMA m2,3 --------------------
    RDA(a45, AhcB, 4);
    SB0();
    STG(B + k2, bcp + 16384);
    BAR();
    LGK(4);  // a23 landed
    PRIO(1);
    MFMA8(2, a23);
    PRIO(0);
    BAR();

    // ---- phase 3: rd a67; STG B1(kt+2)->bc; MFMA m4,5 --------------------
    RDA(a67, AhcB, 6);
    SB0();
    STG(B + K128 + k2, bcp + 24576);
    BAR();
    LGK(4);  // a45 landed
    PRIO(1);
    MFMA8(4, a45);
    PRIO(0);
    BAR();

    // ---- phase 4: gate; MFMA m6,7 + bfr rotate; then STG A0 --------------
    VM4();   // tile kt+1 fully landed (per-wave): oldest 8 of 12
    LGK(0);  // all bc A-reads drained -> any wave's later STG A0 is safe
    BAR();   // global: tile kt+1 landed everywhere; all bc A-reads done
    PRIO(1);
#pragma unroll
    for (int n = 0; n < 4; ++n) {
      // consume bfr[n] (tile kt) ...
      MF(a67[0][0], bfr[n][0], acc[6][n]);
      MF(a67[0][1], bfr[n][1], acc[6][n]);
      MF(a67[1][0], bfr[n][0], acc[7][n]);
      MF(a67[1][1], bfr[n][1], acc[7][n]);
      // ... then refill with tile kt+1 (WAR-ordered via register deps)
      bfr[n][0] = ldsa(BhnB + n * 2048u + s0b);
      bfr[n][1] = ldsa(BhnB + n * 2048u + s1b);
    }
    PRIO(0);
    SB0();
    STG(A + k2, bcp);  // after all reads: no fresh DMA ahead of refills
    BAR();
  }
#undef STG
#undef MFMA8
#undef RDA
}

// ---------------- generic NT GEMM, 256^2 (uniform GEMMs: qkv/proj) --------
template <int MODE, typename OutT>
__global__ __launch_bounds__(512, 2) void gemm256_nt(
    const unsigned short* __restrict__ A, const unsigned short* __restrict__ B,
    OutT* __restrict__ C, const float* __restrict__ bias, float alpha,
    int N, int K, size_t sA, size_t sB, size_t sC) {
  // bijective XCD swizzle (nwg % 8 == 0 for all launches)
  int lin = blockIdx.y * gridDim.x + blockIdx.x;
  const int nwg = gridDim.x * gridDim.y;
  lin = (lin & 7) * (nwg >> 3) + (lin >> 3);
  const int bm = (lin / gridDim.x) * 256;
  const int bn = (lin % gridDim.x) * 256;
  if (MODE == 1 && bn >= bm + 256) return;
  int Keff = K;
  if (MODE == 2) { int kl = bm + 256; Keff = kl < K ? kl : K; }

  A += (size_t)blockIdx.z * sA + (size_t)bm * K;
  B += (size_t)blockIdx.z * sB + (size_t)bn * K;
  C += (size_t)blockIdx.z * sC;

  __shared__ unsigned short smem[65536];  // 128 KiB
  f32x4_t acc[8][4] = {};
  g256_kloop(A, B, K, Keff, smem, acc);

  const int tid = threadIdx.x;
  const int lane = tid & 63;
  const int wave = tid >> 6;
  const int wr = wave >> 2, wc = wave & 3;
  const int fr = lane & 15, q4 = lane >> 4;
  const int r0 = bm + wr * 128 + q4 * 4;
  const int c0 = bn + wc * 64 + fr;
#pragma unroll
  for (int n = 0; n < 4; ++n) {
    const int col = c0 + n * 16;
    const float bs = bias ? bias[col] : 0.f;
#pragma unroll
    for (int m = 0; m < 8; ++m) {
      const int row = r0 + m * 16;
#pragma unroll
      for (int r = 0; r < 4; ++r) {
        float v = acc[m][n][r] * alpha + bs;
        if constexpr (std::is_same_v<OutT, float>)
          C[(size_t)(row + r) * N + col] = v;
        else
          C[(size_t)(row + r) * N + col] = f2bf(v);
      }
    }
  }
}

// ---------------- fused QKV GEMM: N = 3*D, triple-destination epilogue -----
__global__ __launch_bounds__(512, 2) void gemm256_qkv(
    const unsigned short* __restrict__ A, const unsigned short* __restrict__ Bw,
    unsigned short* __restrict__ Q, unsigned short* __restrict__ Kd,
    unsigned short* __restrict__ Vt,
    const float* __restrict__ bq, const float* __restrict__ bk,
    const float* __restrict__ bv, int K, int D, int S) {
  int lin = blockIdx.y * gridDim.x + blockIdx.x;
  const int nwg = gridDim.x * gridDim.y;
  lin = (lin & 7) * (nwg >> 3) + (lin >> 3);
  const int bm = (lin / gridDim.x) * 256;
  const int bn = (lin % gridDim.x) * 256;

  __shared__ unsigned short smem[65536];
  f32x4_t acc[8][4] = {};
  g256_kloop(A + (size_t)bm * K, Bw + (size_t)bn * K, K, K, smem, acc);

  const int tid = threadIdx.x;
  const int lane = tid & 63;
  const int wave = tid >> 6;
  const int wr = wave >> 2, wc = wave & 3;
  const int fr = lane & 15, q4 = lane >> 4;
  const int r0 = bm + wr * 128 + q4 * 4;
  const int c0 = bn + wc * 64 + fr;
#pragma unroll
  for (int n = 0; n < 4; ++n) {
    const int col = c0 + n * 16;              // [0, 3D)
    const int sel = col >> 11;                // 0:Q 1:K 2:V (D=2048)
    const int idx = col & (D - 1);
    const float bs = (sel == 0 ? bq : sel == 1 ? bk : bv)[idx];
#pragma unroll
    for (int m = 0; m < 8; ++m) {
      const int row = r0 + m * 16;
      if (sel < 2) {
        unsigned short* dst = sel == 0 ? Q : Kd;
#pragma unroll
        for (int r = 0; r < 4; ++r)
          dst[(size_t)(row + r) * D + idx] = f2bf(acc[m][n][r] + bs);
      } else {
        const int b = row >> 11;              // S=2048
        const int s = row & (S - 1);          // multiple of 4
        ushort4 pack;
        pack.x = f2bf(acc[m][n][0] + bs);
        pack.y = f2bf(acc[m][n][1] + bs);
        pack.z = f2bf(acc[m][n][2] + bs);
        pack.w = f2bf(acc[m][n][3] + bs);
        *(ushort4*)&Vt[(size_t)b * D * S + (size_t)idx * S + s] = pack;
      }
    }
  }
}

// ---------------- causal softmax: fp32 scores row -> bf16 attn row ----------
// Writes only [0, ceil256(q+1)): PV-128 reads P[row][0..ceil128(q+1)) and
// ceil128 <= ceil256; beyond is never read.
__global__ __launch_bounds__(256) void softmax_causal(
    const float* __restrict__ Sc, unsigned short* __restrict__ P, int n) {
  const int row = blockIdx.x;
  const int q = row & (n - 1);
  const float* srow = Sc + (size_t)row * n;
  unsigned short* prow = P + (size_t)row * n;
  const int tid = threadIdx.x, lane = tid & 63, wid = tid >> 6;
  __shared__ float red[4];

  float m = -3.0e38f;
  for (int j = tid; j <= q; j += 256) m = fmaxf(m, srow[j]);
#pragma unroll
  for (int o = 32; o; o >>= 1) m = fmaxf(m, __shfl_down(m, o, 64));
  if (lane == 0) red[wid] = m;
  __syncthreads();
  m = fmaxf(fmaxf(red[0], red[1]), fmaxf(red[2], red[3]));
  __syncthreads();

  float s = 0.f;
  for (int j = tid; j <= q; j += 256) s += __expf(srow[j] - m);
#pragma unroll
  for (int o = 32; o; o >>= 1) s += __shfl_down(s, o, 64);
  if (lane == 0) red[wid] = s;
  __syncthreads();
  s = red[0] + red[1] + red[2] + red[3];
  const float inv = 1.f / s;

  const int nwrite = ((q >> 8) + 1) << 8;  // ceil256(q+1)
  for (int j = tid; j < nwrite; j += 256) {
    float v = (j <= q) ? __expf(srow[j] - m) * inv : 0.f;
    prow[j] = f2bf(v);
  }
}

// ---------------------------------------------------------------------------
extern "C" void kernel_launch(void* const* d_in, const int* in_sizes, int n_in,
                              void* d_out, int out_size, void* d_ws, size_t ws_size,
                              hipStream_t stream) {
  const int B = 4, S = 2048, D = 2048;
  const int M = B * S;  // 8192

  const float* x  = (const float*)d_in[0];
  // d_in[1] = mask: guaranteed causal tril, hardcoded in kernels
  const float* Wq = (const float*)d_in[2];
  const float* bq = (const float*)d_in[3];
  const float* Wk = (const float*)d_in[4];
  const float* bk = (const float*)d_in[5];
  const float* Wv = (const float*)d_in[6];
  const float* bv = (const float*)d_in[7];
  const float* Wp = (const float*)d_in[8];
  const float* bp = (const float*)d_in[9];
  float* out = (float*)d_out;

  char* ws = (char*)d_ws;
  const size_t MB = 1ull << 20;
  unsigned short* xb   = (unsigned short*)(ws + 0);
  unsigned short* wqkv = (unsigned short*)(ws + 32 * MB);  // [6144,2048]
  unsigned short* wpb  = (unsigned short*)(ws + 56 * MB);
  unsigned short* qb   = (unsigned short*)(ws + 64 * MB);
  unsigned short* kb   = (unsigned short*)(ws + 96 * MB);
  unsigned short* vtb  = (unsigned short*)(ws + 160 * MB);
  float*          sc   = (float*)(ws + 192 * MB);
  unsigned short* pb   = qb;  // attn reuses Q (dead after scores GEMM)
  unsigned short* cb   = kb;  // ctx reuses K (dead after scores GEMM)

  const long nx = (long)M * D;
  const long nw = (long)D * D;

  // 1) casts: x, then all 4 weights in one launch (into stacked layout)
  cast_f32_bf16<<<dim3((unsigned)((nx / 4 + 255) / 256)), 256, 0, stream>>>(x, xb, nx / 4);
  cast_w4<<<dim3((unsigned)((nw / 4 + 255) / 256), 4), 256, 0, stream>>>(
      Wq, Wk, Wv, Wp,
      wqkv, wqkv + (size_t)D * D, wqkv + 2 * (size_t)D * D, wpb, nw / 4);

  // 2) fused QKV projection (N=6144, 768 blocks, 256^2); V written transposed
  gemm256_qkv<<<dim3(3 * D / 256, M / 256), dim3(512), 0, stream>>>(
      xb, wqkv, qb, kb, vtb, bq, bk, bv, D, D, S);

  // 3) scores = Q K^T * inv_std (fp32 out, causal block skip) -- 128^2 for
  //    balance: 544 active blocks vs 144 at 256^2.
  const float inv_std = 1.f / sqrtf((float)D);
  gemm128_nt<1, float><<<dim3(S / BN, S / BM, B), dim3(256), 0, stream>>>(
      qb, kb, sc, nullptr, inv_std, S, S, D, (size_t)S * D, (size_t)S * D, (size_t)S * S);

  // 4) causal softmax -> bf16 attn (writes only to ceil256(q+1))
  softmax_causal<<<dim3(B * S), dim3(256), 0, stream>>>(sc, pb, S);

  // 5) ctx = attn @ V (via V^T, NT form; K capped at diagonal) -- 128^2 for
  //    depth balance: 1024 blocks avg depth 17 vs 256 blocks wall-depth 32.
  gemm128_nt<2, unsigned short><<<dim3(D / BN, S / BM, B), dim3(256), 0, stream>>>(
      pb, vtb, cb, nullptr, 1.f, S, D, S, (size_t)S * S, (size_t)D * S, (size_t)S * D);

  // 6) out = ctx Wp^T + bp (fp32 out, 256^2: 256 blocks uniform)
  gemm256_nt<0, float><<<dim3(D / 256, M / 256), dim3(512), 0, stream>>>(
      cb, wpb, out, bp, 1.f, D, D, 0, 0, 0);
}

// Round 7
// 632.479 us; speedup vs baseline: 1.0341x; 1.0341x over previous
//
#include <hip/hip_runtime.h>
#include <hip/hip_bf16.h>
#include <type_traits>
#include <math.h>

// ---------------------------------------------------------------------------
// Attention: out = softmax_causal((x Wq^T + bq)(x Wk^T + bk)^T / sqrt(D)) (x Wv^T + bv) Wp^T + bp
// B=4, S=2048, D=2048, fp32 in/out, bf16 MFMA compute.
//
// R10: 256^2 K-loop rewritten as the documented 8-phase QUADRANT template
// (own-phase reads + operand reuse), the one schedule cell not yet tested
// clean. R9's 128^2 dispatch-balance experiment regressed (654us) -> scores/
// PV reverted to 256^2 (R6 config, best=599us). Softmax write-trim kept.
//
// Per K-tile (4 phases, per-wave C = 128x64 = 4 quadrants of 64x32):
//   ph1{rd A-half0(8) + B-half0(4) | STG A1(kt+1)->nb | lgk(8) | BAR |
//       lgk(0) | MFMA Q00 | BAR}
//   ph2{rd B-half1(4) | BAR | lgk(0) | MFMA Q01 | BAR}
//   ph3{rd A-half1(8) | STG B0(kt+2),B1(kt+2)->bc | BAR | lgk(0) |
//       MFMA Q10 (reuses bf0 regs) | BAR}
//   ph4{STG A0(kt+2)->bc | vmcnt(6) | BAR | MFMA Q11 (reuses bf1) | BAR}
// Region liveness (own-phase reads): wave wr reads ONLY block-half A{wr}
//   (m0-3 at ph1, m4-7 at ph3) -> A regions dead after ph3; wave wc reads
//   ONLY B-half {wc>>1} (n0-1 ph1, n2-3 ph2) -> B regions dead after ph2.
//   Each read batch is drained by its phase's lgk(0) BEFORE that phase's
//   closing barrier -> any later-phase STG into the region is globally safe.
//   Stage slots: A1(kt+1)@ph1 (region dead since kt-1 ph3); B0,B1(kt+2)@ph3
//   (dead after ph2); A0(kt+2)@ph4 (dead after ph3).
// vmcnt ledger (2 loads per STG): queue/tile = [A1(kt+1)@ph1][B0,B1(kt+2)@
//   ph3][A0(kt+2)@ph4]. At ph4 after A0 issue: 7 halves = 14 loads out-
//   standing; vmcnt(6) retires oldest 8 = ALL of tile kt+1; BAR globalizes
//   before kt+1's ph1 reads. Prologue stages tile0{A0,A1,B0,B1}+tile1{B0,B1,
//   A0} (14 loads), vmcnt(6) -> tile0 landed, 6 in flight = steady state.
//   Wrapped k mod Keff past-the-end stages land only in dead regions.
// XOR slot swizzle kept (0 bank conflicts). Bijective XCD swizzle kept.
// asm ds_read + naked counted waits + SB0 pins (rule #18) kept from R8.
//
// Workspace layout (256 MB):
//   [0,32)MB    xb    bf16 x              [8192,2048]
//   [32,56)MB   wqkv  bf16 [Wq;Wk;Wv]     [6144,2048]
//   [56,64)MB   wpb   bf16 Wp             [2048,2048]
//   [64,96)MB   qb    bf16 Q              (later reused as attn P)
//   [96,128)MB  kb    bf16 K              (later reused as ctx)
//   [160,192)MB vtb   bf16 V^T per batch  [B][D][S]
//   [192,256)MB sc    fp32 scores         [B,S,S]
// ---------------------------------------------------------------------------

typedef __bf16 bf16x8_t __attribute__((ext_vector_type(8)));
typedef float f32x4_t __attribute__((ext_vector_type(4)));
typedef unsigned short u16x8_t __attribute__((ext_vector_type(8)));

__device__ inline unsigned short f2bf(float f) {
  unsigned int u = __builtin_bit_cast(unsigned int, f);
  unsigned int r = u + 0x7fffu + ((u >> 16) & 1u);
  return (unsigned short)(r >> 16);
}

// async global->LDS, 16B per lane; lds dest = wave-uniform base + lane*16
__device__ inline void gl2lds16(const unsigned short* g, unsigned short* l) {
  __builtin_amdgcn_global_load_lds(
      (const __attribute__((address_space(1))) unsigned int*)g,
      (__attribute__((address_space(3))) unsigned int*)l, 16, 0, 0);
}

// LDS byte-address of a generic pointer known to be in LDS
__device__ __forceinline__ unsigned as3base(const unsigned short* p) {
  return (unsigned)(unsigned long long)
      (const __attribute__((address_space(3))) unsigned short*)p;
}

// raw ds_read_b128, invisible to the waitcnt legalizer (manual lgkmcnt!)
__device__ __forceinline__ bf16x8_t ldsa(unsigned a) {
  bf16x8_t r;
  asm volatile("ds_read_b128 %0, %1" : "=v"(r) : "v"(a));
  return r;
}

#define MF(a_, b_, c_) \
  (c_) = __builtin_amdgcn_mfma_f32_16x16x32_bf16((a_), (b_), (c_), 0, 0, 0)
#define SB0() __builtin_amdgcn_sched_barrier(0)
#define BAR()                         \
  do {                                \
    SB0();                            \
    __builtin_amdgcn_s_barrier();     \
    SB0();                            \
  } while (0)
#define LGK(n_)                                          \
  do {                                                   \
    asm volatile("s_waitcnt lgkmcnt(" #n_ ")");          \
    SB0();                                               \
  } while (0)
#define VM6()                                   \
  do {                                          \
    asm volatile("s_waitcnt vmcnt(6)");         \
    SB0();                                      \
  } while (0)
#define PRIO(x) __builtin_amdgcn_s_setprio(x)

// ---------------- cast fp32 -> bf16 (x input) ------------------------------
__global__ __launch_bounds__(256) void cast_f32_bf16(
    const float* __restrict__ in, unsigned short* __restrict__ out, long n4) {
  long i = blockIdx.x * 256L + threadIdx.x;
  if (i >= n4) return;
  float4 f = ((const float4*)in)[i];
  ushort4 u;
  u.x = f2bf(f.x); u.y = f2bf(f.y); u.z = f2bf(f.z); u.w = f2bf(f.w);
  ((ushort4*)out)[i] = u;
}

// ---------------- fused 4-weight cast: blockIdx.y selects matrix -----------
__global__ __launch_bounds__(256) void cast_w4(
    const float* __restrict__ w0, const float* __restrict__ w1,
    const float* __restrict__ w2, const float* __restrict__ w3,
    unsigned short* __restrict__ o0, unsigned short* __restrict__ o1,
    unsigned short* __restrict__ o2, unsigned short* __restrict__ o3,
    long n4) {
  long i = blockIdx.x * 256L + threadIdx.x;
  if (i >= n4) return;
  const float* in; unsigned short* out;
  switch (blockIdx.y) {
    case 0: in = w0; out = o0; break;
    case 1: in = w1; out = o1; break;
    case 2: in = w2; out = o2; break;
    default: in = w3; out = o3; break;
  }
  float4 f = ((const float4*)in)[i];
  ushort4 u;
  u.x = f2bf(f.x); u.y = f2bf(f.y); u.z = f2bf(f.z); u.w = f2bf(f.w);
  ((ushort4*)out)[i] = u;
}

// ===================== 256^2 quadrant-template K-loop ======================
// LDS bytes: buf b at b*65536; A0@0 A1@16384 B0@32768 B1@49152.
// Each half = [128 rows][64 cols] bf16, 16 KB; staged by 512 thr x 2 loads.
__device__ __forceinline__ void g256_kloop(
    const unsigned short* __restrict__ A, const unsigned short* __restrict__ B,
    int K, int Keff, unsigned short* smem, f32x4_t (&acc)[8][4]) {
  const int tid = threadIdx.x;
  const int lane = tid & 63;
  const int wave = tid >> 6;
  const int wr = wave >> 2;           // 0..1  (M half)
  const int wc = wave & 3;            // 0..3  (N quarter)
  const int fr = lane & 15;
  const int q4 = lane >> 4;
  // swizzled 16B slot byte-offsets (phys slot p of row r holds logical p^(r&7))
  const unsigned s0b = (unsigned)((q4 ^ (fr & 7)) * 16);        // kk=0
  const unsigned s1b = (unsigned)(((q4 + 4) ^ (fr & 7)) * 16);  // kk=1
  // staging: this thread's global offset (row + swizzled column)
  const size_t rowK =
      (size_t)(wave * 8 + (lane >> 3)) * (size_t)K +
      (size_t)(((lane & 7) ^ ((lane >> 3) & 7)) * 8);
  const size_t K64 = (size_t)64 * K;
  const size_t K128 = (size_t)128 * K;
  const int wofs = wave * 512;  // wave-uniform LDS chunk (1 KB, elems)
  const int NT = Keff >> 6;
  const unsigned sb = as3base(smem);
  const unsigned aoffB = (unsigned)(wr * 16384 + fr * 128);
  const unsigned boffB =
      (unsigned)(32768 + (wc >> 1) * 16384 + (wc & 1) * 8192 + fr * 128);

#define STG(gp_, lh_)                        \
  do {                                       \
    const unsigned short* g_ = (gp_) + rowK; \
    gl2lds16(g_, (lh_) + wofs);              \
    gl2lds16(g_ + K64, (lh_) + 4096 + wofs); \
  } while (0)

// read 4 A m-subtiles (one A-half of this wave's 128 rows) into af
#define RDAF(baseB_, mo_)                                     \
  _Pragma("unroll")                                           \
  for (int m = 0; m < 4; ++m) {                               \
    af[m][0] = ldsa((baseB_) + (m + (mo_)) * 2048u + s0b);    \
    af[m][1] = ldsa((baseB_) + (m + (mo_)) * 2048u + s1b);    \
  }

// read 2 B n-subtiles (one B-half of this wave's 64 cols) into dst
#define RDB(dst_, baseB_, no_)                                \
  _Pragma("unroll")                                           \
  for (int n = 0; n < 2; ++n) {                               \
    dst_[n][0] = ldsa((baseB_) + (n + (no_)) * 2048u + s0b);  \
    dst_[n][1] = ldsa((baseB_) + (n + (no_)) * 2048u + s1b);  \
  }

// one C-quadrant: 4 m-subtiles x 2 n-subtiles x 2 kk = 16 MFMA
#define MFQ(mb_, nb_, bsrc_)                                  \
  _Pragma("unroll")                                           \
  for (int m = 0; m < 4; ++m)                                 \
    _Pragma("unroll")                                         \
    for (int n = 0; n < 2; ++n) {                             \
      MF(af[m][0], bsrc_[n][0], acc[(mb_) + m][(nb_) + n]);   \
      MF(af[m][1], bsrc_[n][1], acc[(mb_) + m][(nb_) + n]);   \
    }

  // ---- prologue: tile0 {A0,A1,B0,B1} -> buf0; tile1 {B0,B1,A0} -> buf1 ----
  STG(A, smem);
  STG(A + K128, smem + 8192);
  STG(B, smem + 16384);
  STG(B + K128, smem + 24576);
  STG(B + 64, smem + 32768 + 16384);
  STG(B + K128 + 64, smem + 32768 + 24576);
  STG(A + 64, smem + 32768);
  VM6();   // tile0's 8 loads landed (per-wave); 6 in flight = steady state
  BAR();   // now landed for ALL waves

  bf16x8_t af[4][2], bf0[2][2], bf1[2][2];

  for (int kt = 0; kt < NT; ++kt) {
    unsigned short* bcp = smem + ((kt & 1) << 15);       // compute buf (elems)
    unsigned short* nbp = smem + (((kt + 1) & 1) << 15); // next buf (elems)
    const unsigned AhcB = sb + ((unsigned)(kt & 1) << 16) + aoffB;
    const unsigned BhcB = sb + ((unsigned)(kt & 1) << 16) + boffB;
    int k1 = (kt + 1) << 6; if (k1 >= Keff) k1 -= Keff;  // wrap = safe garbage
    int k2 = (kt + 2) << 6; if (k2 >= Keff) k2 -= Keff;

    // ---- ph1: rd A-half0 + B-half0 (12); STG A1(kt+1)->nb; MFMA Q00 ------
    RDAF(AhcB, 0);
    RDB(bf0, BhcB, 0);
    SB0();
    STG(A + K128 + k1, nbp + 8192);
    LGK(8);  // optional queue cap: oldest 4 of 12 landed pre-barrier
    BAR();
    LGK(0);  // all 12 landed (queue drained during barrier convergence)
    PRIO(1);
    MFQ(0, 0, bf0);
    PRIO(0);
    BAR();

    // ---- ph2: rd B-half1 (4); MFMA Q01 (af reused) -----------------------
    RDB(bf1, BhcB, 2);
    SB0();
    BAR();
    LGK(0);
    PRIO(1);
    MFQ(0, 2, bf1);
    PRIO(0);
    BAR();

    // ---- ph3: rd A-half1 (8); STG B0,B1(kt+2)->bc; MFMA Q10 (bf0 regs) ---
    RDAF(AhcB, 4);
    SB0();
    STG(B + k2, bcp + 16384);
    STG(B + K128 + k2, bcp + 24576);
    BAR();
    LGK(0);
    PRIO(1);
    MFQ(4, 0, bf0);
    PRIO(0);
    BAR();

    // ---- ph4: STG A0(kt+2)->bc; vmcnt(6); MFMA Q11 (af+bf1 regs) ---------
    STG(A + k2, bcp);
    VM6();   // oldest 8 of 14 = ALL of tile kt+1 landed (per-wave)
    BAR();   // globalized before kt+1's ph1 reads
    PRIO(1);
    MFQ(4, 2, bf1);
    PRIO(0);
    BAR();
  }
#undef STG
#undef RDAF
#undef RDB
#undef MFQ
}

// ---------------- generic NT GEMM (modes 0/1/2), 256^2 --------------------
// MODE 0: plain. MODE 1: causal block skip. MODE 2: causal K-limit.
template <int MODE, typename OutT>
__global__ __launch_bounds__(512, 2) void gemm256_nt(
    const unsigned short* __restrict__ A, const unsigned short* __restrict__ B,
    OutT* __restrict__ C, const float* __restrict__ bias, float alpha,
    int N, int K, size_t sA, size_t sB, size_t sC) {
  // bijective XCD swizzle (nwg % 8 == 0 for all launches)
  int lin = blockIdx.y * gridDim.x + blockIdx.x;
  const int nwg = gridDim.x * gridDim.y;
  lin = (lin & 7) * (nwg >> 3) + (lin >> 3);
  const int bm = (lin / gridDim.x) * 256;
  const int bn = (lin % gridDim.x) * 256;
  if (MODE == 1 && bn >= bm + 256) return;
  int Keff = K;
  if (MODE == 2) { int kl = bm + 256; Keff = kl < K ? kl : K; }

  A += (size_t)blockIdx.z * sA + (size_t)bm * K;
  B += (size_t)blockIdx.z * sB + (size_t)bn * K;
  C += (size_t)blockIdx.z * sC;

  __shared__ unsigned short smem[65536];  // 128 KiB
  f32x4_t acc[8][4] = {};
  g256_kloop(A, B, K, Keff, smem, acc);

  const int tid = threadIdx.x;
  const int lane = tid & 63;
  const int wave = tid >> 6;
  const int wr = wave >> 2, wc = wave & 3;
  const int fr = lane & 15, q4 = lane >> 4;
  const int r0 = bm + wr * 128 + q4 * 4;
  const int c0 = bn + wc * 64 + fr;
#pragma unroll
  for (int n = 0; n < 4; ++n) {
    const int col = c0 + n * 16;
    const float bs = bias ? bias[col] : 0.f;
#pragma unroll
    for (int m = 0; m < 8; ++m) {
      const int row = r0 + m * 16;
#pragma unroll
      for (int r = 0; r < 4; ++r) {
        float v = acc[m][n][r] * alpha + bs;
        if constexpr (std::is_same_v<OutT, float>)
          C[(size_t)(row + r) * N + col] = v;
        else
          C[(size_t)(row + r) * N + col] = f2bf(v);
      }
    }
  }
}

// ---------------- fused QKV GEMM: N = 3*D, triple-destination epilogue -----
__global__ __launch_bounds__(512, 2) void gemm256_qkv(
    const unsigned short* __restrict__ A, const unsigned short* __restrict__ Bw,
    unsigned short* __restrict__ Q, unsigned short* __restrict__ Kd,
    unsigned short* __restrict__ Vt,
    const float* __restrict__ bq, const float* __restrict__ bk,
    const float* __restrict__ bv, int K, int D, int S) {
  int lin = blockIdx.y * gridDim.x + blockIdx.x;
  const int nwg = gridDim.x * gridDim.y;
  lin = (lin & 7) * (nwg >> 3) + (lin >> 3);
  const int bm = (lin / gridDim.x) * 256;
  const int bn = (lin % gridDim.x) * 256;

  __shared__ unsigned short smem[65536];
  f32x4_t acc[8][4] = {};
  g256_kloop(A + (size_t)bm * K, Bw + (size_t)bn * K, K, K, smem, acc);

  const int tid = threadIdx.x;
  const int lane = tid & 63;
  const int wave = tid >> 6;
  const int wr = wave >> 2, wc = wave & 3;
  const int fr = lane & 15, q4 = lane >> 4;
  const int r0 = bm + wr * 128 + q4 * 4;
  const int c0 = bn + wc * 64 + fr;
#pragma unroll
  for (int n = 0; n < 4; ++n) {
    const int col = c0 + n * 16;              // [0, 3D)
    const int sel = col >> 11;                // 0:Q 1:K 2:V (D=2048)
    const int idx = col & (D - 1);
    const float bs = (sel == 0 ? bq : sel == 1 ? bk : bv)[idx];
#pragma unroll
    for (int m = 0; m < 8; ++m) {
      const int row = r0 + m * 16;
      if (sel < 2) {
        unsigned short* dst = sel == 0 ? Q : Kd;
#pragma unroll
        for (int r = 0; r < 4; ++r)
          dst[(size_t)(row + r) * D + idx] = f2bf(acc[m][n][r] + bs);
      } else {
        const int b = row >> 11;              // S=2048
        const int s = row & (S - 1);          // multiple of 4
        ushort4 pack;
        pack.x = f2bf(acc[m][n][0] + bs);
        pack.y = f2bf(acc[m][n][1] + bs);
        pack.z = f2bf(acc[m][n][2] + bs);
        pack.w = f2bf(acc[m][n][3] + bs);
        *(ushort4*)&Vt[(size_t)b * D * S + (size_t)idx * S + s] = pack;
      }
    }
  }
}

// ---------------- causal softmax: fp32 scores row -> bf16 attn row ----------
// Writes only [0, ceil256(q+1)): PV-256 reads P[row][0..Keff=ceil256(q+1)).
__global__ __launch_bounds__(256) void softmax_causal(
    const float* __restrict__ Sc, unsigned short* __restrict__ P, int n) {
  const int row = blockIdx.x;
  const int q = row & (n - 1);
  const float* srow = Sc + (size_t)row * n;
  unsigned short* prow = P + (size_t)row * n;
  const int tid = threadIdx.x, lane = tid & 63, wid = tid >> 6;
  __shared__ float red[4];

  float m = -3.0e38f;
  for (int j = tid; j <= q; j += 256) m = fmaxf(m, srow[j]);
#pragma unroll
  for (int o = 32; o; o >>= 1) m = fmaxf(m, __shfl_down(m, o, 64));
  if (lane == 0) red[wid] = m;
  __syncthreads();
  m = fmaxf(fmaxf(red[0], red[1]), fmaxf(red[2], red[3]));
  __syncthreads();

  float s = 0.f;
  for (int j = tid; j <= q; j += 256) s += __expf(srow[j] - m);
#pragma unroll
  for (int o = 32; o; o >>= 1) s += __shfl_down(s, o, 64);
  if (lane == 0) red[wid] = s;
  __syncthreads();
  s = red[0] + red[1] + red[2] + red[3];
  const float inv = 1.f / s;

  const int nwrite = ((q >> 8) + 1) << 8;  // ceil256(q+1)
  for (int j = tid; j < nwrite; j += 256) {
    float v = (j <= q) ? __expf(srow[j] - m) * inv : 0.f;
    prow[j] = f2bf(v);
  }
}

// ---------------------------------------------------------------------------
extern "C" void kernel_launch(void* const* d_in, const int* in_sizes, int n_in,
                              void* d_out, int out_size, void* d_ws, size_t ws_size,
                              hipStream_t stream) {
  const int B = 4, S = 2048, D = 2048;
  const int M = B * S;  // 8192

  const float* x  = (const float*)d_in[0];
  // d_in[1] = mask: guaranteed causal tril, hardcoded in kernels
  const float* Wq = (const float*)d_in[2];
  const float* bq = (const float*)d_in[3];
  const float* Wk = (const float*)d_in[4];
  const float* bk = (const float*)d_in[5];
  const float* Wv = (const float*)d_in[6];
  const float* bv = (const float*)d_in[7];
  const float* Wp = (const float*)d_in[8];
  const float* bp = (const float*)d_in[9];
  float* out = (float*)d_out;

  char* ws = (char*)d_ws;
  const size_t MB = 1ull << 20;
  unsigned short* xb   = (unsigned short*)(ws + 0);
  unsigned short* wqkv = (unsigned short*)(ws + 32 * MB);  // [6144,2048]
  unsigned short* wpb  = (unsigned short*)(ws + 56 * MB);
  unsigned short* qb   = (unsigned short*)(ws + 64 * MB);
  unsigned short* kb   = (unsigned short*)(ws + 96 * MB);
  unsigned short* vtb  = (unsigned short*)(ws + 160 * MB);
  float*          sc   = (float*)(ws + 192 * MB);
  unsigned short* pb   = qb;  // attn reuses Q (dead after scores GEMM)
  unsigned short* cb   = kb;  // ctx reuses K (dead after scores GEMM)

  const long nx = (long)M * D;
  const long nw = (long)D * D;

  // 1) casts: x, then all 4 weights in one launch (into stacked layout)
  cast_f32_bf16<<<dim3((unsigned)((nx / 4 + 255) / 256)), 256, 0, stream>>>(x, xb, nx / 4);
  cast_w4<<<dim3((unsigned)((nw / 4 + 255) / 256), 4), 256, 0, stream>>>(
      Wq, Wk, Wv, Wp,
      wqkv, wqkv + (size_t)D * D, wqkv + 2 * (size_t)D * D, wpb, nw / 4);

  const dim3 blk(512);

  // 2) fused QKV projection (N=6144, 768 blocks); V written transposed
  gemm256_qkv<<<dim3(3 * D / 256, M / 256), blk, 0, stream>>>(
      xb, wqkv, qb, kb, vtb, bq, bk, bv, D, D, S);

  // 3) scores = Q K^T * inv_std (fp32 out, causal block skip)
  const float inv_std = 1.f / sqrtf((float)D);
  gemm256_nt<1, float><<<dim3(S / 256, S / 256, B), blk, 0, stream>>>(
      qb, kb, sc, nullptr, inv_std, S, D, (size_t)S * D, (size_t)S * D, (size_t)S * S);

  // 4) causal softmax -> bf16 attn (writes only to ceil256(q+1))
  softmax_causal<<<dim3(B * S), dim3(256), 0, stream>>>(sc, pb, S);

  // 5) ctx = attn @ V  (via V^T, NT form; K-range capped at diagonal)
  gemm256_nt<2, unsigned short><<<dim3(D / 256, S / 256, B), blk, 0, stream>>>(
      pb, vtb, cb, nullptr, 1.f, D, S, (size_t)S * S, (size_t)D * S, (size_t)S * D);

  // 6) out = ctx Wp^T + bp (fp32 out)
  gemm256_nt<0, float><<<dim3(D / 256, M / 256), blk, 0, stream>>>(
      cb, wpb, out, bp, 1.f, D, D, 0, 0, 0);
}